// Round 5
// baseline (452.342 us; speedup 1.0000x reference)
//
#include <hip/hip_runtime.h>
#include <hip/hip_bf16.h>

typedef __bf16 bf16x8 __attribute__((ext_vector_type(8)));
typedef __bf16 bf16x4 __attribute__((ext_vector_type(4)));
typedef float  f32x4  __attribute__((ext_vector_type(4)));
typedef unsigned u32x4 __attribute__((ext_vector_type(4)));

#define B_ 4
#define T_ 2048
#define H_ 16
#define D_ 64
#define C_ 1024
#define M_ 8192                    // B*T
#define NE_ ((size_t)M_ * C_)      // elems per (M,C) tensor
#define KVSTR_ 2048                // row stride of fused K|V tensor

// ---------------------------------------------------------------------------
// Probe: flag=1 if inputs are fp32, flag=0 if bf16.
// ---------------------------------------------------------------------------
__global__ void probe_dtype(const unsigned short* __restrict__ x,
                            int* __restrict__ flag)
{
  __shared__ float red[256];
  float m = 0.0f;
  for (int i = threadIdx.x; i < 4096; i += 256) {
    unsigned int u = ((unsigned int)x[i]) << 16;
    float v = fabsf(__uint_as_float(u));
    if (!(v <= 1e30f)) v = 1e31f;
    m = fmaxf(m, v);
  }
  red[threadIdx.x] = m;
  __syncthreads();
  for (int s = 128; s > 0; s >>= 1) {
    if (threadIdx.x < s) red[threadIdx.x] = fmaxf(red[threadIdx.x], red[threadIdx.x + s]);
    __syncthreads();
  }
  if (threadIdx.x == 0) *flag = (red[0] > 100.0f) ? 1 : 0;
}

__device__ __forceinline__ float load1_adapt(const void* p, size_t idx, int f)
{
  if (f) return ((const float*)p)[idx];
  return __bfloat162float(((const __hip_bfloat16*)p)[idx]);
}

// ---------------------------------------------------------------------------
// Convert a tensor to bf16 (fp32 src if flag, else plain bf16 copy).
// ---------------------------------------------------------------------------
__global__ __launch_bounds__(256) void cvt_bf16(
    const int* __restrict__ flagp, const void* __restrict__ src,
    __bf16* __restrict__ dst, int n)
{
  const int f = *flagp;
  for (size_t i = ((size_t)blockIdx.x * 256 + threadIdx.x) * 8; i < (size_t)n;
       i += (size_t)gridDim.x * 2048) {
    bf16x8 r;
    if (f) {
      const float* pf = (const float*)src + i;
      float4 a = *(const float4*)pf;
      float4 b = *(const float4*)(pf + 4);
      r[0] = (__bf16)a.x; r[1] = (__bf16)a.y; r[2] = (__bf16)a.z; r[3] = (__bf16)a.w;
      r[4] = (__bf16)b.x; r[5] = (__bf16)b.y; r[6] = (__bf16)b.z; r[7] = (__bf16)b.w;
    } else {
      r = *(const bf16x8*)((const __bf16*)src + i);
    }
    *(bf16x8*)(dst + i) = r;
  }
}

// ---------------------------------------------------------------------------
// async 16B global -> LDS copy (gfx950 global_load_lds dwordx4)
// ---------------------------------------------------------------------------
__device__ __forceinline__ void g2lds16(const __bf16* g, __bf16* l)
{
  __builtin_amdgcn_global_load_lds(
      (const __attribute__((address_space(1))) void*)g,
      (__attribute__((address_space(3))) void*)l, 16, 0, 0);
}

// pack two f32 -> one u32 of two bf16 (RNE), single HW instruction
__device__ __forceinline__ unsigned cvtpk_bf16(float lo, float hi)
{
  unsigned r;
  asm("v_cvt_pk_bf16_f32 %0, %1, %2" : "=v"(r) : "v"(lo), "v"(hi));
  return r;
}

// ---------------------------------------------------------------------------
// m97-style GEMM: C = A * Bm^T. A: MxK bf16, Bm: NxK bf16. 128x128 tile,
// BK=64, 4 waves (2x2), global_load_lds width-16 staging (unpadded LDS).
// XCD-aware swizzle (nwg % 8 == 0 for all launches here).
// Output: bf16, or fp32 when (adaptive && *flagp).
// ---------------------------------------------------------------------------
__global__ __launch_bounds__(256) void gemm128(
    const __bf16* __restrict__ A, const __bf16* __restrict__ Bm,
    void* __restrict__ C, int M, int N, int K,
    const int* __restrict__ flagp, int adaptive)
{
  __shared__ __bf16 As[128][64];
  __shared__ __bf16 Bs[128][64];

  const int tid  = threadIdx.x;
  const int wv   = tid >> 6;
  const int lane = tid & 63;
  const int n16  = lane & 15;
  const int quad = lane >> 4;
  const int wm = (wv & 1) * 64, wn = (wv >> 1) * 64;

  const int nwgx = gridDim.x;
  const int id   = blockIdx.y * nwgx + blockIdx.x;
  const int cpx  = (nwgx * gridDim.y) >> 3;
  const int swz  = (id & 7) * cpx + (id >> 3);
  const int m0 = (swz % nwgx) * 128, n0 = (swz / nwgx) * 128;

  f32x4 acc[4][4];
#pragma unroll
  for (int i = 0; i < 4; i++)
#pragma unroll
    for (int j = 0; j < 4; j++) acc[i][j] = (f32x4){0.f, 0.f, 0.f, 0.f};

  const int trow = tid >> 3;          // 0..31
  const int tcol = (tid & 7) * 8;     // 0..56

  for (int k0 = 0; k0 < K; k0 += 64) {
#pragma unroll
    for (int p = 0; p < 4; p++) {
      g2lds16(A  + (size_t)(m0 + trow + p * 32) * K + k0 + tcol,
              &As[trow + p * 32][tcol]);
      g2lds16(Bm + (size_t)(n0 + trow + p * 32) * K + k0 + tcol,
              &Bs[trow + p * 32][tcol]);
    }
    __syncthreads();   // drains vmcnt(0): LDS is valid

#pragma unroll
    for (int kk = 0; kk < 2; kk++) {
      bf16x8 af[4], bf[4];
#pragma unroll
      for (int i = 0; i < 4; i++) {
        af[i] = *(const bf16x8*)&As[wm + i * 16 + n16][kk * 32 + quad * 8];
        bf[i] = *(const bf16x8*)&Bs[wn + i * 16 + n16][kk * 32 + quad * 8];
      }
#pragma unroll
      for (int i = 0; i < 4; i++)
#pragma unroll
        for (int j = 0; j < 4; j++)
          acc[i][j] = __builtin_amdgcn_mfma_f32_16x16x32_bf16(af[i], bf[j],
                                                              acc[i][j], 0, 0, 0);
    }
    __syncthreads();
  }

  const int f = adaptive ? *flagp : 0;
  const int rb = quad * 4;
#pragma unroll
  for (int i = 0; i < 4; i++)
#pragma unroll
    for (int j = 0; j < 4; j++)
#pragma unroll
      for (int r = 0; r < 4; r++) {
        const size_t idx = (size_t)(m0 + wm + i * 16 + rb + r) * N
                           + n0 + wn + j * 16 + n16;
        if (f) ((float*)C)[idx] = acc[i][j][r];
        else   ((__bf16*)C)[idx] = (__bf16)acc[i][j][r];
      }
}

// ---------------------------------------------------------------------------
// Fused rmsnorm+RoPE on q (stride 1024) and k (in fused kv, stride 2048),
// plus v mix (kv stride 2048, col +1024).
// ---------------------------------------------------------------------------
__global__ __launch_bounds__(256) void fuse_rope_vmix(
    const int* __restrict__ flagp,
    __hip_bfloat16* __restrict__ q,
    __hip_bfloat16* __restrict__ kv,
    const void* __restrict__ v1,
    const void* __restrict__ lambp)
{
  const int f    = *flagp;
  const int task = blockIdx.x * 4 + (threadIdx.x >> 6);
  const int lane = threadIdx.x & 63;
  const int h  = task & 15;
  const int bt = task >> 4;
  const int t  = bt & (T_ - 1);
  const size_t baseq = (size_t)bt * C_ + h * D_ + lane;
  const size_t basek = (size_t)bt * KVSTR_ + h * D_ + lane;

  const int j = lane & 31;
  const float inv = expf(-(float)j * (9.2103403719761836f / 32.0f));
  const float ang = (float)t * inv;
  const float cs = cosf(ang), sn = sinf(ang);
  const float EPS = 0.0078125f;

  {
    float xv = __bfloat162float(q[baseq]);
    float ss = xv * xv;
#pragma unroll
    for (int off = 32; off >= 1; off >>= 1) ss += __shfl_xor(ss, off);
    float r  = rsqrtf(ss * (1.0f / 64.0f) + EPS);
    float xn = xv * r;
    float pr = __shfl_xor(xn, 32);
    float yv = (lane < 32) ? (xn * cs + pr * sn) : (pr * -sn + xn * cs);
    q[baseq] = __float2bfloat16(yv);
  }
  {
    float xv = __bfloat162float(kv[basek]);
    float ss = xv * xv;
#pragma unroll
    for (int off = 32; off >= 1; off >>= 1) ss += __shfl_xor(ss, off);
    float r  = rsqrtf(ss * (1.0f / 64.0f) + EPS);
    float xn = xv * r;
    float pr = __shfl_xor(xn, 32);
    float yv = (lane < 32) ? (xn * cs + pr * sn) : (pr * -sn + xn * cs);
    kv[basek] = __float2bfloat16(yv);
  }
  {
    float lam = load1_adapt(lambp, 0, f);
    float vv  = __bfloat162float(kv[basek + 1024]);
    float v1v = load1_adapt(v1, baseq, f);
    kv[basek + 1024] = __float2bfloat16((1.0f - lam) * vv + lam * v1v);
  }
}

// ---------------------------------------------------------------------------
// Transpose mixed V (cols 1024..2047 of kv, stride 2048) ->
// VT [b*16+h][d][t] (row = d, contiguous in t). 64x64 tiles via LDS.
// ---------------------------------------------------------------------------
__global__ __launch_bounds__(256) void transp_v(
    const __bf16* __restrict__ kv, __bf16* __restrict__ vt)
{
  __shared__ __bf16 Ts[64][72];
  const int bh = blockIdx.y;          // 0..63
  const int t0 = blockIdx.x * 64;
  const int b = bh >> 4, h = bh & 15;

  const int r = threadIdx.x >> 2;           // 0..63 (t-local)
  const int c = (threadIdx.x & 3) * 16;     // 0,16,32,48 (d)
  const __bf16* src = kv + (size_t)(b * T_ + t0 + r) * KVSTR_ + 1024 + h * D_ + c;
  *(bf16x8*)&Ts[r][c]     = *(const bf16x8*)src;
  *(bf16x8*)&Ts[r][c + 8] = *(const bf16x8*)(src + 8);
  __syncthreads();

  const int d  = threadIdx.x >> 2;          // 0..63
  const int tc = (threadIdx.x & 3) * 16;    // t-chunk
  bf16x8 o0, o1;
#pragma unroll
  for (int jj = 0; jj < 8; jj++) { o0[jj] = Ts[tc + jj][d]; o1[jj] = Ts[tc + 8 + jj][d]; }
  __bf16* dst = vt + (size_t)(bh * D_ + d) * T_ + t0 + tc;
  *(bf16x8*)dst       = o0;
  *(bf16x8*)(dst + 8) = o1;
}

// ---------------------------------------------------------------------------
// One s-tile of the attention inner loop (QK^T swapped, fixed-max softmax,
// in-register P redistribution, PV). Inlined; all indexing static.
// ---------------------------------------------------------------------------
__device__ __forceinline__ void attn_tile(
    const bf16x8 (&KF)[4][2], const bf16x8 (&VF)[4][2],
    const bf16x8 (&aq)[2][2], f32x4 (&Ot)[2][4], float (&l_lane)[2],
    int s0, int rbase0, int n16, int quad, int srcA, int srcB, bool lowq)
{
#pragma unroll
  for (int rt = 0; rt < 2; rt++) {
    const int rbase = rbase0 + rt * 16;
    if (s0 <= rbase + 15) {
      // ---- S^T = K Q^T : lane holds S[q=rbase+n16, s=s0+16t+quad*4+r]
      f32x4 S[4];
      __builtin_amdgcn_s_setprio(1);
#pragma unroll
      for (int t = 0; t < 4; t++) {
        S[t] = (f32x4){0.f, 0.f, 0.f, 0.f};
        S[t] = __builtin_amdgcn_mfma_f32_16x16x32_bf16(KF[t][0], aq[rt][0], S[t], 0, 0, 0);
        S[t] = __builtin_amdgcn_mfma_f32_16x16x32_bf16(KF[t][1], aq[rt][1], S[t], 0, 0, 0);
      }
      __builtin_amdgcn_s_setprio(0);

      // ---- causal mask (only when tile crosses this row-tile's diagonal)
      if (s0 + 63 > rbase) {
        const int tg = rbase + n16;
#pragma unroll
        for (int t = 0; t < 4; t++) {
#pragma unroll
          for (int r = 0; r < 4; r++) {
            const int sg = s0 + t * 16 + quad * 4 + r;
            if (sg > tg) S[t][r] = -1e30f;
          }
        }
      }

      // ---- fixed-max softmax: p = exp(S - 8); l accumulates in-lane
      float p[4][4];
#pragma unroll
      for (int t = 0; t < 4; t++)
#pragma unroll
        for (int r = 0; r < 4; r++)
          p[t][r] = __expf(S[t][r] - 8.0f);
      l_lane[rt] += ((p[0][0] + p[0][1]) + (p[0][2] + p[0][3]))
                  + ((p[1][0] + p[1][1]) + (p[1][2] + p[1][3]))
                  + ((p[2][0] + p[2][1]) + (p[2][2] + p[2][3]))
                  + ((p[3][0] + p[3][1]) + (p[3][2] + p[3][3]));

      // ---- pack to bf16 pairs ----
      unsigned pk0[4], pk1[4];
#pragma unroll
      for (int t = 0; t < 4; t++) {
        pk0[t] = cvtpk_bf16(p[t][0], p[t][1]);
        pk1[t] = cvtpk_bf16(p[t][2], p[t][3]);
      }

      // ---- in-register redistribution to PV B-fragments ----
      bf16x8 pf[2];
#pragma unroll
      for (int c = 0; c < 2; c++) {
        const int tE = 2 * c, tO = 2 * c + 1;
        unsigned a0 = (unsigned)__shfl((int)pk0[tE], srcA);
        unsigned a1 = (unsigned)__shfl((int)pk0[tO], srcA);
        unsigned b0 = (unsigned)__shfl((int)pk1[tE], srcA);
        unsigned b1 = (unsigned)__shfl((int)pk1[tO], srcA);
        unsigned c0 = (unsigned)__shfl((int)pk0[tE], srcB);
        unsigned c1 = (unsigned)__shfl((int)pk0[tO], srcB);
        unsigned d0 = (unsigned)__shfl((int)pk1[tE], srcB);
        unsigned d1 = (unsigned)__shfl((int)pk1[tO], srcB);
        union { u32x4 u; bf16x8 bv; } uw;
        uw.u[0] = lowq ? a0 : a1;
        uw.u[1] = lowq ? b0 : b1;
        uw.u[2] = lowq ? c0 : c1;
        uw.u[3] = lowq ? d0 : d1;
        pf[c] = uw.bv;
      }

      // ---- O^T += V^T P^T (A = VF, B = pf) ----
      __builtin_amdgcn_s_setprio(1);
#pragma unroll
      for (int t = 0; t < 4; t++) {
        Ot[rt][t] = __builtin_amdgcn_mfma_f32_16x16x32_bf16(VF[t][0], pf[0], Ot[rt][t], 0, 0, 0);
        Ot[rt][t] = __builtin_amdgcn_mfma_f32_16x16x32_bf16(VF[t][1], pf[1], Ot[rt][t], 0, 0, 0);
      }
      __builtin_amdgcn_s_setprio(0);
    }
  }
}

// ---------------------------------------------------------------------------
// MFMA flash attention fwd (causal), BARRIER-FREE / LDS-FREE, with s-tile
// REGISTER DOUBLE-BUFFER: next tile's 16 K/V fragment loads are issued before
// computing the current tile (named A/B sets, manually 2-unrolled loop ->
// static indexing), so L2 latency hides under a full tile of compute.
// K read from fused kv (stride 2048); V^T from pre-transposed VT.
// FIXED-MAX softmax (rmsnorm => S in [-8,8]). Swapped operands throughout.
// Head-clustered XCD swizzle; heavy blocks first. y aliases q.
// ---------------------------------------------------------------------------
__global__ __launch_bounds__(256, 2) void attn_mfma(
    const __bf16* q,
    const __bf16* __restrict__ kv,
    const __bf16* __restrict__ vt,
    __bf16* y)
{
  const int tid  = threadIdx.x;
  const int wv   = tid >> 6;
  const int lane = tid & 63;
  const int n16  = lane & 15;
  const int quad = lane >> 4;

  const int id = blockIdx.y * gridDim.x + blockIdx.x;   // 0..1023
  const int bh = (id & 7) + 8 * ((id >> 3) & 7);        // 0..63
  const int bx = id >> 6;                               // 0..15
  const int b = bh >> 4, h = bh & 15;
  const int q0 = (gridDim.x - 1 - bx) * 128;            // heavy first
  const size_t hb  = (size_t)b * T_ * C_ + h * D_;      // q/y base (stride C_)
  const size_t hbk = (size_t)b * T_ * KVSTR_ + h * D_;  // k base (stride 2048)
  const size_t vhb = (size_t)bh * D_ * T_;              // vt base

  // ---- Q fragments (B-operand of swapped QK), pre-scaled by 1/8 ----
  bf16x8 aq[2][2];
#pragma unroll
  for (int rt = 0; rt < 2; rt++) {
    const size_t qoff = hb + (size_t)(q0 + wv * 32 + rt * 16 + n16) * C_;
    aq[rt][0] = *(const bf16x8*)(q + qoff + quad * 8);
    aq[rt][1] = *(const bf16x8*)(q + qoff + 32 + quad * 8);
#pragma unroll
    for (int jj = 0; jj < 8; jj++) {
      aq[rt][0][jj] = (__bf16)((float)aq[rt][0][jj] * 0.125f);
      aq[rt][1][jj] = (__bf16)((float)aq[rt][1][jj] * 0.125f);
    }
  }

  f32x4 Ot[2][4];
  float l_lane[2];
#pragma unroll
  for (int rt = 0; rt < 2; rt++) {
    l_lane[rt] = 0.0f;
#pragma unroll
    for (int t = 0; t < 4; t++) Ot[rt][t] = (f32x4){0.f, 0.f, 0.f, 0.f};
  }

  const int srcA = n16 + 32 * (quad & 1);
  const int srcB = srcA + 16;
  const bool lowq = quad < 2;

  const int rbase0 = q0 + wv * 32;
  const int niter  = (rbase0 + 31) / 64 + 1;   // per-wave s-range

#define LOADF(KF, VF, S0_)                                                   \
  do {                                                                       \
    _Pragma("unroll")                                                        \
    for (int t = 0; t < 4; t++) {                                            \
      const __bf16* kp = kv + hbk + (size_t)((S0_) + t * 16 + n16) * KVSTR_; \
      KF[t][0] = *(const bf16x8*)(kp + quad * 8);                            \
      KF[t][1] = *(const bf16x8*)(kp + 32 + quad * 8);                       \
      const __bf16* vp = vt + vhb + (size_t)(t * 16 + n16) * T_ + (S0_);     \
      VF[t][0] = *(const bf16x8*)(vp + quad * 8);                            \
      VF[t][1] = *(const bf16x8*)(vp + 32 + quad * 8);                       \
    }                                                                        \
  } while (0)

  bf16x8 kfA[4][2], vfA[4][2], kfB[4][2], vfB[4][2];
  LOADF(kfA, vfA, 0);

  int it = 0;
  for (;;) {
    int s0 = it * 64;
    bool hn = (it + 1 < niter);
    if (hn) LOADF(kfB, vfB, s0 + 64);
    attn_tile(kfA, vfA, aq, Ot, l_lane, s0, rbase0, n16, quad, srcA, srcB, lowq);
    if (!hn) break;
    ++it;
    s0 = it * 64;
    hn = (it + 1 < niter);
    if (hn) LOADF(kfA, vfA, s0 + 64);
    attn_tile(kfB, vfB, aq, Ot, l_lane, s0, rbase0, n16, quad, srcA, srcB, lowq);
    if (!hn) break;
    ++it;
  }
#undef LOADF

  // ---- epilogue: reduce l across quads (same n16 = same q-row), write O
#pragma unroll
  for (int rt = 0; rt < 2; rt++) {
    float lt = l_lane[rt];
    lt += __shfl_xor(lt, 16);
    lt += __shfl_xor(lt, 32);
    const float linv = 1.0f / lt;
    const int qrow = q0 + wv * 32 + rt * 16 + n16;
#pragma unroll
    for (int t = 0; t < 4; t++) {
      bf16x4 o;
#pragma unroll
      for (int r = 0; r < 4; r++) o[r] = (__bf16)(Ot[rt][t][r] * linv);
      *(bf16x4*)(y + hb + (size_t)qrow * C_ + t * 16 + quad * 4) = o;
    }
  }
}

// ---------------------------------------------------------------------------
__global__ __launch_bounds__(256) void copy_v1(
    const int* __restrict__ flagp, const void* __restrict__ v1, void* __restrict__ out)
{
  const int f = *flagp;
  const size_t nbytes = NE_ * (f ? 4u : 2u);
  const uint4* s = (const uint4*)v1;
  uint4* d = (uint4*)((char*)out + nbytes);
  const size_t n16 = nbytes / 16;
  for (size_t i = (size_t)blockIdx.x * 256 + threadIdx.x; i < n16;
       i += (size_t)gridDim.x * 256)
    d[i] = s[i];
}

// ---------------------------------------------------------------------------
extern "C" void kernel_launch(void* const* d_in, const int* in_sizes, int n_in,
                              void* d_out, int out_size, void* d_ws, size_t ws_size,
                              hipStream_t stream)
{
  const void* x    = d_in[0];
  const void* v1   = d_in[1];
  const void* Wq   = d_in[2];
  const void* Wk   = d_in[3];
  const void* Wv   = d_in[4];
  const void* Wp   = d_in[5];
  const void* lamb = d_in[6];

  // ws layout (bf16): xb | qw | Wq | Wk | Wv | Wp | flag  (~42 MB)
  // xb is dead after the QKV GEMMs -> reused as VT (exactly NE_ elems).
  __bf16* xb  = (__bf16*)d_ws;
  __bf16* qw  = xb + NE_;
  __bf16* wqb = qw + NE_;
  __bf16* wkb = wqb + (size_t)C_ * C_;
  __bf16* wvb = wkb + (size_t)C_ * C_;   // contiguous after wkb (fused N=2048)
  __bf16* wpb = wvb + (size_t)C_ * C_;
  int* flagp  = (int*)(wpb + (size_t)C_ * C_);
  __bf16* vtb = xb;                       // VT alias (16 MB)
  // fused K|V [M][2048] staged in d_out (32 MB; exact fit under bf16,
  // first half under fp32). Dead before the final proj/copy writes.
  __bf16* kvw = (__bf16*)d_out;

  probe_dtype<<<1, 256, 0, stream>>>((const unsigned short*)x, flagp);

  cvt_bf16<<<4096, 256, 0, stream>>>(flagp, x,  xb,  (int)NE_);
  cvt_bf16<<<512,  256, 0, stream>>>(flagp, Wq, wqb, C_ * C_);
  cvt_bf16<<<512,  256, 0, stream>>>(flagp, Wk, wkb, C_ * C_);
  cvt_bf16<<<512,  256, 0, stream>>>(flagp, Wv, wvb, C_ * C_);
  cvt_bf16<<<512,  256, 0, stream>>>(flagp, Wp, wpb, C_ * C_);

  // Q GEMM (N=1024) and fused K|V GEMM (N=2048, Wk/Wv contiguous)
  gemm128<<<dim3(M_ / 128, 8),  256, 0, stream>>>(xb, wqb, qw,  M_, 1024, C_, flagp, 0);
  gemm128<<<dim3(M_ / 128, 16), 256, 0, stream>>>(xb, wkb, kvw, M_, 2048, C_, flagp, 0);

  fuse_rope_vmix<<<(M_ * H_) / 4, 256, 0, stream>>>(
      flagp, (__hip_bfloat16*)qw, (__hip_bfloat16*)kvw, v1, lamb);

  // V -> VT (xb is dead now)
  transp_v<<<dim3(T_ / 64, B_ * H_), 256, 0, stream>>>(kvw, vtb);

  attn_mfma<<<dim3(T_ / 128, B_ * H_), 256, 0, stream>>>(qw, kvw, vtb, qw);

  gemm128<<<dim3(M_ / 128, 8), 256, 0, stream>>>(qw, wpb, d_out, M_, 1024, C_, flagp, 1);
  copy_v1<<<8192, 256, 0, stream>>>(flagp, v1, d_out);
}

// Round 6
// 444.025 us; speedup vs baseline: 1.0187x; 1.0187x over previous
//
#include <hip/hip_runtime.h>
#include <hip/hip_bf16.h>

typedef __bf16 bf16x8 __attribute__((ext_vector_type(8)));
typedef __bf16 bf16x4 __attribute__((ext_vector_type(4)));
typedef float  f32x4  __attribute__((ext_vector_type(4)));
typedef float  f32x16 __attribute__((ext_vector_type(16)));
typedef unsigned u32x4 __attribute__((ext_vector_type(4)));

#define B_ 4
#define T_ 2048
#define H_ 16
#define D_ 64
#define C_ 1024
#define M_ 8192                    // B*T
#define NE_ ((size_t)M_ * C_)      // elems per (M,C) tensor
#define KVSTR_ 2048                // row stride of fused K|V tensor

// ---------------------------------------------------------------------------
// Probe: flag=1 if inputs are fp32, flag=0 if bf16.
// ---------------------------------------------------------------------------
__global__ void probe_dtype(const unsigned short* __restrict__ x,
                            int* __restrict__ flag)
{
  __shared__ float red[256];
  float m = 0.0f;
  for (int i = threadIdx.x; i < 4096; i += 256) {
    unsigned int u = ((unsigned int)x[i]) << 16;
    float v = fabsf(__uint_as_float(u));
    if (!(v <= 1e30f)) v = 1e31f;
    m = fmaxf(m, v);
  }
  red[threadIdx.x] = m;
  __syncthreads();
  for (int s = 128; s > 0; s >>= 1) {
    if (threadIdx.x < s) red[threadIdx.x] = fmaxf(red[threadIdx.x], red[threadIdx.x + s]);
    __syncthreads();
  }
  if (threadIdx.x == 0) *flag = (red[0] > 100.0f) ? 1 : 0;
}

__device__ __forceinline__ float load1_adapt(const void* p, size_t idx, int f)
{
  if (f) return ((const float*)p)[idx];
  return __bfloat162float(((const __hip_bfloat16*)p)[idx]);
}

// ---------------------------------------------------------------------------
// Convert a tensor to bf16 (fp32 src if flag, else plain bf16 copy).
// ---------------------------------------------------------------------------
__global__ __launch_bounds__(256) void cvt_bf16(
    const int* __restrict__ flagp, const void* __restrict__ src,
    __bf16* __restrict__ dst, int n)
{
  const int f = *flagp;
  for (size_t i = ((size_t)blockIdx.x * 256 + threadIdx.x) * 8; i < (size_t)n;
       i += (size_t)gridDim.x * 2048) {
    bf16x8 r;
    if (f) {
      const float* pf = (const float*)src + i;
      float4 a = *(const float4*)pf;
      float4 b = *(const float4*)(pf + 4);
      r[0] = (__bf16)a.x; r[1] = (__bf16)a.y; r[2] = (__bf16)a.z; r[3] = (__bf16)a.w;
      r[4] = (__bf16)b.x; r[5] = (__bf16)b.y; r[6] = (__bf16)b.z; r[7] = (__bf16)b.w;
    } else {
      r = *(const bf16x8*)((const __bf16*)src + i);
    }
    *(bf16x8*)(dst + i) = r;
  }
}

// ---------------------------------------------------------------------------
// async 16B global -> LDS copy (gfx950 global_load_lds dwordx4)
// ---------------------------------------------------------------------------
__device__ __forceinline__ void g2lds16(const __bf16* g, __bf16* l)
{
  __builtin_amdgcn_global_load_lds(
      (const __attribute__((address_space(1))) void*)g,
      (__attribute__((address_space(3))) void*)l, 16, 0, 0);
}

// pack two f32 -> one u32 of two bf16 (RNE), single HW instruction
__device__ __forceinline__ unsigned cvtpk_bf16(float lo, float hi)
{
  unsigned r;
  asm("v_cvt_pk_bf16_f32 %0, %1, %2" : "=v"(r) : "v"(lo), "v"(hi));
  return r;
}

// ---------------------------------------------------------------------------
// m97-style GEMM: C = A * Bm^T. A: MxK bf16, Bm: NxK bf16. 128x128 tile,
// BK=64, 4 waves (2x2), global_load_lds width-16 staging (unpadded LDS).
// XCD-aware swizzle (nwg % 8 == 0 for all launches here).
// Output: bf16, or fp32 when (adaptive && *flagp).
// ---------------------------------------------------------------------------
__global__ __launch_bounds__(256) void gemm128(
    const __bf16* __restrict__ A, const __bf16* __restrict__ Bm,
    void* __restrict__ C, int M, int N, int K,
    const int* __restrict__ flagp, int adaptive)
{
  __shared__ __bf16 As[128][64];
  __shared__ __bf16 Bs[128][64];

  const int tid  = threadIdx.x;
  const int wv   = tid >> 6;
  const int lane = tid & 63;
  const int n16  = lane & 15;
  const int quad = lane >> 4;
  const int wm = (wv & 1) * 64, wn = (wv >> 1) * 64;

  const int nwgx = gridDim.x;
  const int id   = blockIdx.y * nwgx + blockIdx.x;
  const int cpx  = (nwgx * gridDim.y) >> 3;
  const int swz  = (id & 7) * cpx + (id >> 3);
  const int m0 = (swz % nwgx) * 128, n0 = (swz / nwgx) * 128;

  f32x4 acc[4][4];
#pragma unroll
  for (int i = 0; i < 4; i++)
#pragma unroll
    for (int j = 0; j < 4; j++) acc[i][j] = (f32x4){0.f, 0.f, 0.f, 0.f};

  const int trow = tid >> 3;          // 0..31
  const int tcol = (tid & 7) * 8;     // 0..56

  for (int k0 = 0; k0 < K; k0 += 64) {
#pragma unroll
    for (int p = 0; p < 4; p++) {
      g2lds16(A  + (size_t)(m0 + trow + p * 32) * K + k0 + tcol,
              &As[trow + p * 32][tcol]);
      g2lds16(Bm + (size_t)(n0 + trow + p * 32) * K + k0 + tcol,
              &Bs[trow + p * 32][tcol]);
    }
    __syncthreads();   // drains vmcnt(0): LDS is valid

#pragma unroll
    for (int kk = 0; kk < 2; kk++) {
      bf16x8 af[4], bf[4];
#pragma unroll
      for (int i = 0; i < 4; i++) {
        af[i] = *(const bf16x8*)&As[wm + i * 16 + n16][kk * 32 + quad * 8];
        bf[i] = *(const bf16x8*)&Bs[wn + i * 16 + n16][kk * 32 + quad * 8];
      }
#pragma unroll
      for (int i = 0; i < 4; i++)
#pragma unroll
        for (int j = 0; j < 4; j++)
          acc[i][j] = __builtin_amdgcn_mfma_f32_16x16x32_bf16(af[i], bf[j],
                                                              acc[i][j], 0, 0, 0);
    }
    __syncthreads();
  }

  const int f = adaptive ? *flagp : 0;
  const int rb = quad * 4;
#pragma unroll
  for (int i = 0; i < 4; i++)
#pragma unroll
    for (int j = 0; j < 4; j++)
#pragma unroll
      for (int r = 0; r < 4; r++) {
        const size_t idx = (size_t)(m0 + wm + i * 16 + rb + r) * N
                           + n0 + wn + j * 16 + n16;
        if (f) ((float*)C)[idx] = acc[i][j][r];
        else   ((__bf16*)C)[idx] = (__bf16)acc[i][j][r];
      }
}

// ---------------------------------------------------------------------------
// Fused rmsnorm+RoPE on q (stride 1024) and k (in fused kv, stride 2048),
// plus v mix (kv stride 2048, col +1024).
// ---------------------------------------------------------------------------
__global__ __launch_bounds__(256) void fuse_rope_vmix(
    const int* __restrict__ flagp,
    __hip_bfloat16* __restrict__ q,
    __hip_bfloat16* __restrict__ kv,
    const void* __restrict__ v1,
    const void* __restrict__ lambp)
{
  const int f    = *flagp;
  const int task = blockIdx.x * 4 + (threadIdx.x >> 6);
  const int lane = threadIdx.x & 63;
  const int h  = task & 15;
  const int bt = task >> 4;
  const int t  = bt & (T_ - 1);
  const size_t baseq = (size_t)bt * C_ + h * D_ + lane;
  const size_t basek = (size_t)bt * KVSTR_ + h * D_ + lane;

  const int j = lane & 31;
  const float inv = expf(-(float)j * (9.2103403719761836f / 32.0f));
  const float ang = (float)t * inv;
  const float cs = cosf(ang), sn = sinf(ang);
  const float EPS = 0.0078125f;

  {
    float xv = __bfloat162float(q[baseq]);
    float ss = xv * xv;
#pragma unroll
    for (int off = 32; off >= 1; off >>= 1) ss += __shfl_xor(ss, off);
    float r  = rsqrtf(ss * (1.0f / 64.0f) + EPS);
    float xn = xv * r;
    float pr = __shfl_xor(xn, 32);
    float yv = (lane < 32) ? (xn * cs + pr * sn) : (pr * -sn + xn * cs);
    q[baseq] = __float2bfloat16(yv);
  }
  {
    float xv = __bfloat162float(kv[basek]);
    float ss = xv * xv;
#pragma unroll
    for (int off = 32; off >= 1; off >>= 1) ss += __shfl_xor(ss, off);
    float r  = rsqrtf(ss * (1.0f / 64.0f) + EPS);
    float xn = xv * r;
    float pr = __shfl_xor(xn, 32);
    float yv = (lane < 32) ? (xn * cs + pr * sn) : (pr * -sn + xn * cs);
    kv[basek] = __float2bfloat16(yv);
  }
  {
    float lam = load1_adapt(lambp, 0, f);
    float vv  = __bfloat162float(kv[basek + 1024]);
    float v1v = load1_adapt(v1, baseq, f);
    kv[basek + 1024] = __float2bfloat16((1.0f - lam) * vv + lam * v1v);
  }
}

// ---------------------------------------------------------------------------
// Transpose mixed V (cols 1024..2047 of kv, stride 2048) ->
// VT [b*16+h][d][t] (row = d, contiguous in t). 64x64 tiles via LDS.
// ---------------------------------------------------------------------------
__global__ __launch_bounds__(256) void transp_v(
    const __bf16* __restrict__ kv, __bf16* __restrict__ vt)
{
  __shared__ __bf16 Ts[64][72];
  const int bh = blockIdx.y;          // 0..63
  const int t0 = blockIdx.x * 64;
  const int b = bh >> 4, h = bh & 15;

  const int r = threadIdx.x >> 2;           // 0..63 (t-local)
  const int c = (threadIdx.x & 3) * 16;     // 0,16,32,48 (d)
  const __bf16* src = kv + (size_t)(b * T_ + t0 + r) * KVSTR_ + 1024 + h * D_ + c;
  *(bf16x8*)&Ts[r][c]     = *(const bf16x8*)src;
  *(bf16x8*)&Ts[r][c + 8] = *(const bf16x8*)(src + 8);
  __syncthreads();

  const int d  = threadIdx.x >> 2;          // 0..63
  const int tc = (threadIdx.x & 3) * 16;    // t-chunk
  bf16x8 o0, o1;
#pragma unroll
  for (int jj = 0; jj < 8; jj++) { o0[jj] = Ts[tc + jj][d]; o1[jj] = Ts[tc + 8 + jj][d]; }
  __bf16* dst = vt + (size_t)(bh * D_ + d) * T_ + t0 + tc;
  *(bf16x8*)dst       = o0;
  *(bf16x8*)(dst + 8) = o1;
}

// ---------------------------------------------------------------------------
// MFMA flash attention fwd (causal), 32x32x16 geometry (m214 structure).
// 4 waves/block, each owns 32 q-rows; s-tile 64 = two 32x32 S^T tiles.
// Swapped QK^T (S^T = mfma(K,Q)): lane(q=lane&31, hi=lane>>5) holds
// S[s=8g+4*hi+m][q], g=reg>>2, m=reg&3. FIXED-MAX softmax (S in [-8,8]).
// P -> PV B-frag: cvt_pk packs s-adjacent pairs; ONE v_permlane32_swap per
// word-pair fills both hi'-halves (new_x={x.lo,y.lo} = jw<2 words,
// new_y={x.hi,y.hi} = jw>=2 words). Zero LDS ops in the kernel.
// K from fused kv (stride 2048, L2-resident, head-clustered XCD swizzle);
// V^T from pre-transposed VT. Heavy blocks first. y aliases q.
// ---------------------------------------------------------------------------
__global__ __launch_bounds__(256, 3) void attn_mfma(
    const __bf16* q,
    const __bf16* __restrict__ kv,
    const __bf16* __restrict__ vt,
    __bf16* y)
{
  const int tid  = threadIdx.x;
  const int wv   = tid >> 6;
  const int lane = tid & 63;
  const int l31  = lane & 31;
  const int hi   = lane >> 5;

  const int id = blockIdx.y * gridDim.x + blockIdx.x;   // 0..1023
  const int bh = (id & 7) + 8 * ((id >> 3) & 7);        // 0..63 (xcd = bh&7)
  const int bx = id >> 6;                               // 0..15
  const int b = bh >> 4, h = bh & 15;
  const int q0 = (gridDim.x - 1 - bx) * 128;            // heavy first
  const size_t hb  = (size_t)b * T_ * C_ + h * D_;      // q/y base (stride C_)
  const size_t hbk = (size_t)b * T_ * KVSTR_ + h * D_;  // k base (stride 2048)
  const size_t vhb = (size_t)bh * D_ * T_;              // vt base

  const int qbase = q0 + wv * 32;

  // ---- Q fragments (B-op of swapped QK): lane holds Q[qbase+l31][16i+8hi+j]
  bf16x8 aq[4];
  {
    const __bf16* qp = q + hb + (size_t)(qbase + l31) * C_ + hi * 8;
#pragma unroll
    for (int i = 0; i < 4; i++) {
      aq[i] = *(const bf16x8*)(qp + 16 * i);
#pragma unroll
      for (int jj = 0; jj < 8; jj++)
        aq[i][jj] = (__bf16)((float)aq[i][jj] * 0.125f);
    }
  }

  f32x16 Ot0, Ot1;                 // O^T[d = 32*dh + 8g+4hi+m][q = l31]
#pragma unroll
  for (int r = 0; r < 16; r++) { Ot0[r] = 0.f; Ot1[r] = 0.f; }
  float l_lane = 0.f;

  const int niter = (qbase + 31) / 64 + 1;
  for (int it = 0; it < niter; it++) {
    const int s0 = it * 64;
    const int nst = (s0 + 32 <= qbase + 31) ? 2 : 1;

    // ---- K fragments: A[row=s0+32st+l31][k=16i+8hi+j] (L2 hits) ----
    bf16x8 kf[2][4];
#pragma unroll
    for (int st = 0; st < 2; st++) {
      const __bf16* kp = kv + hbk + (size_t)(s0 + 32 * st + l31) * KVSTR_ + hi * 8;
#pragma unroll
      for (int i = 0; i < 4; i++) kf[st][i] = *(const bf16x8*)(kp + 16 * i);
    }
    // ---- V^T fragments: A[row=32dh+l31][k = s0+16sc+8hi+j] ----
    bf16x8 vf[2][4];
#pragma unroll
    for (int dh = 0; dh < 2; dh++) {
      const __bf16* vp = vt + vhb + (size_t)(32 * dh + l31) * T_ + s0 + hi * 8;
#pragma unroll
      for (int sc = 0; sc < 4; sc++) vf[dh][sc] = *(const bf16x8*)(vp + 16 * sc);
    }

    bf16x8 pf[4];
#pragma unroll
    for (int st = 0; st < 2; st++) {
      if (st < nst) {
        // ---- S^T = K Q^T (4 chained k-chunks over D=64) ----
        f32x16 S;
#pragma unroll
        for (int r = 0; r < 16; r++) S[r] = 0.f;
        __builtin_amdgcn_s_setprio(1);
#pragma unroll
        for (int i = 0; i < 4; i++)
          S = __builtin_amdgcn_mfma_f32_32x32x16_bf16(kf[st][i], aq[i], S, 0, 0, 0);
        __builtin_amdgcn_s_setprio(0);

        // ---- causal mask (tile crosses the diagonal) ----
        if (s0 + 32 * st + 31 > qbase) {
          const int tg = qbase + l31;
#pragma unroll
          for (int r = 0; r < 16; r++) {
            const int sg = s0 + 32 * st + (r & 3) + 8 * (r >> 2) + 4 * hi;
            if (sg > tg) S[r] = -1e30f;
          }
        }

        // ---- fixed-max softmax: p = exp(S - 8), lane-local l ----
        float p[16];
#pragma unroll
        for (int r = 0; r < 16; r++) p[r] = __expf(S[r] - 8.0f);
#pragma unroll
        for (int r = 0; r < 16; r++) l_lane += p[r];

        // ---- pack s-adjacent pairs: wg[g][c] = (p[4g+2c], p[4g+2c+1]) ----
        unsigned wg[4][2];
#pragma unroll
        for (int g = 0; g < 4; g++) {
          wg[g][0] = cvtpk_bf16(p[4 * g + 0], p[4 * g + 1]);
          wg[g][1] = cvtpk_bf16(p[4 * g + 2], p[4 * g + 3]);
        }

        // ---- permlane32_swap: {x.lo,y.lo} = hi'=0 words, {x.hi,y.hi} = hi'=1
#pragma unroll
        for (int scl = 0; scl < 2; scl++) {
          unsigned x0 = wg[2 * scl][0], y0 = wg[2 * scl + 1][0];
          unsigned x1 = wg[2 * scl][1], y1 = wg[2 * scl + 1][1];
          asm volatile("v_permlane32_swap_b32 %0, %1" : "+v"(x0), "+v"(y0));
          asm volatile("v_permlane32_swap_b32 %0, %1" : "+v"(x1), "+v"(y1));
          union { u32x4 u; bf16x8 v8; } uw;
          uw.u[0] = x0; uw.u[1] = x1; uw.u[2] = y0; uw.u[3] = y1;
          pf[2 * st + scl] = uw.v8;
        }
      }
    }

    // ---- O^T += V^T P^T ----
    const int nsc = 2 * nst;
    __builtin_amdgcn_s_setprio(1);
#pragma unroll
    for (int sc = 0; sc < 4; sc++)
      if (sc < nsc) {
        Ot0 = __builtin_amdgcn_mfma_f32_32x32x16_bf16(vf[0][sc], pf[sc], Ot0, 0, 0, 0);
        Ot1 = __builtin_amdgcn_mfma_f32_32x32x16_bf16(vf[1][sc], pf[sc], Ot1, 0, 0, 0);
      }
    __builtin_amdgcn_s_setprio(0);
  }

  // ---- epilogue: l = sum over the two hi-halves of this q ----
  l_lane += __shfl_xor(l_lane, 32);
  const float linv = 1.0f / l_lane;
  const int qrow = qbase + l31;
#pragma unroll
  for (int g = 0; g < 4; g++) {
    bf16x4 o0, o1;
#pragma unroll
    for (int m = 0; m < 4; m++) {
      o0[m] = (__bf16)(Ot0[4 * g + m] * linv);
      o1[m] = (__bf16)(Ot1[4 * g + m] * linv);
    }
    const int d0 = 8 * g + 4 * hi;
    *(bf16x4*)(y + hb + (size_t)qrow * C_ + d0)      = o0;
    *(bf16x4*)(y + hb + (size_t)qrow * C_ + 32 + d0) = o1;
  }
}

// ---------------------------------------------------------------------------
__global__ __launch_bounds__(256) void copy_v1(
    const int* __restrict__ flagp, const void* __restrict__ v1, void* __restrict__ out)
{
  const int f = *flagp;
  const size_t nbytes = NE_ * (f ? 4u : 2u);
  const uint4* s = (const uint4*)v1;
  uint4* d = (uint4*)((char*)out + nbytes);
  const size_t n16 = nbytes / 16;
  for (size_t i = (size_t)blockIdx.x * 256 + threadIdx.x; i < n16;
       i += (size_t)gridDim.x * 256)
    d[i] = s[i];
}

// ---------------------------------------------------------------------------
extern "C" void kernel_launch(void* const* d_in, const int* in_sizes, int n_in,
                              void* d_out, int out_size, void* d_ws, size_t ws_size,
                              hipStream_t stream)
{
  const void* x    = d_in[0];
  const void* v1   = d_in[1];
  const void* Wq   = d_in[2];
  const void* Wk   = d_in[3];
  const void* Wv   = d_in[4];
  const void* Wp   = d_in[5];
  const void* lamb = d_in[6];

  // ws layout (bf16): xb | qw | Wq | Wk | Wv | Wp | flag  (~42 MB)
  // xb is dead after the QKV GEMMs -> reused as VT (exactly NE_ elems).
  __bf16* xb  = (__bf16*)d_ws;
  __bf16* qw  = xb + NE_;
  __bf16* wqb = qw + NE_;
  __bf16* wkb = wqb + (size_t)C_ * C_;
  __bf16* wvb = wkb + (size_t)C_ * C_;   // contiguous after wkb (fused N=2048)
  __bf16* wpb = wvb + (size_t)C_ * C_;
  int* flagp  = (int*)(wpb + (size_t)C_ * C_);
  __bf16* vtb = xb;                       // VT alias (16 MB)
  // fused K|V [M][2048] staged in d_out (32 MB; exact fit under bf16,
  // first half under fp32). Dead before the final proj/copy writes.
  __bf16* kvw = (__bf16*)d_out;

  probe_dtype<<<1, 256, 0, stream>>>((const unsigned short*)x, flagp);

  cvt_bf16<<<4096, 256, 0, stream>>>(flagp, x,  xb,  (int)NE_);
  cvt_bf16<<<512,  256, 0, stream>>>(flagp, Wq, wqb, C_ * C_);
  cvt_bf16<<<512,  256, 0, stream>>>(flagp, Wk, wkb, C_ * C_);
  cvt_bf16<<<512,  256, 0, stream>>>(flagp, Wv, wvb, C_ * C_);
  cvt_bf16<<<512,  256, 0, stream>>>(flagp, Wp, wpb, C_ * C_);

  // Q GEMM (N=1024) and fused K|V GEMM (N=2048, Wk/Wv contiguous)
  gemm128<<<dim3(M_ / 128, 8),  256, 0, stream>>>(xb, wqb, qw,  M_, 1024, C_, flagp, 0);
  gemm128<<<dim3(M_ / 128, 16), 256, 0, stream>>>(xb, wkb, kvw, M_, 2048, C_, flagp, 0);

  fuse_rope_vmix<<<(M_ * H_) / 4, 256, 0, stream>>>(
      flagp, (__hip_bfloat16*)qw, (__hip_bfloat16*)kvw, v1, lamb);

  // V -> VT (xb is dead now)
  transp_v<<<dim3(T_ / 64, B_ * H_), 256, 0, stream>>>(kvw, vtb);

  attn_mfma<<<dim3(T_ / 128, B_ * H_), 256, 0, stream>>>(qw, kvw, vtb, qw);

  gemm128<<<dim3(M_ / 128, 8), 256, 0, stream>>>(qw, wpb, d_out, M_, 1024, C_, flagp, 1);
  copy_v1<<<8192, 256, 0, stream>>>(flagp, v1, d_out);
}

// Round 8
// 378.159 us; speedup vs baseline: 1.1962x; 1.1742x over previous
//
#include <hip/hip_runtime.h>
#include <hip/hip_bf16.h>

typedef __bf16 bf16x8 __attribute__((ext_vector_type(8)));
typedef __bf16 bf16x4 __attribute__((ext_vector_type(4)));
typedef float  f32x4  __attribute__((ext_vector_type(4)));
typedef float  f32x16 __attribute__((ext_vector_type(16)));
typedef unsigned u32x4 __attribute__((ext_vector_type(4)));

#define B_ 4
#define T_ 2048
#define H_ 16
#define D_ 64
#define C_ 1024
#define M_ 8192                    // B*T
#define NE_ ((size_t)M_ * C_)      // elems per (M,C) tensor
#define KVSTR_ 2048                // row stride of fused K|V tensor

// ---------------------------------------------------------------------------
// Probe: flag=1 if inputs are fp32, flag=0 if bf16.
// ---------------------------------------------------------------------------
__global__ void probe_dtype(const unsigned short* __restrict__ x,
                            int* __restrict__ flag)
{
  __shared__ float red[256];
  float m = 0.0f;
  for (int i = threadIdx.x; i < 4096; i += 256) {
    unsigned int u = ((unsigned int)x[i]) << 16;
    float v = fabsf(__uint_as_float(u));
    if (!(v <= 1e30f)) v = 1e31f;
    m = fmaxf(m, v);
  }
  red[threadIdx.x] = m;
  __syncthreads();
  for (int s = 128; s > 0; s >>= 1) {
    if (threadIdx.x < s) red[threadIdx.x] = fmaxf(red[threadIdx.x], red[threadIdx.x + s]);
    __syncthreads();
  }
  if (threadIdx.x == 0) *flag = (red[0] > 100.0f) ? 1 : 0;
}

__device__ __forceinline__ float load1_adapt(const void* p, size_t idx, int f)
{
  if (f) return ((const float*)p)[idx];
  return __bfloat162float(((const __hip_bfloat16*)p)[idx]);
}

// ---------------------------------------------------------------------------
// Convert a tensor to bf16 (fp32 src if flag, else plain bf16 copy).
// ---------------------------------------------------------------------------
__global__ __launch_bounds__(256) void cvt_bf16(
    const int* __restrict__ flagp, const void* __restrict__ src,
    __bf16* __restrict__ dst, int n)
{
  const int f = *flagp;
  for (size_t i = ((size_t)blockIdx.x * 256 + threadIdx.x) * 8; i < (size_t)n;
       i += (size_t)gridDim.x * 2048) {
    bf16x8 r;
    if (f) {
      const float* pf = (const float*)src + i;
      float4 a = *(const float4*)pf;
      float4 b = *(const float4*)(pf + 4);
      r[0] = (__bf16)a.x; r[1] = (__bf16)a.y; r[2] = (__bf16)a.z; r[3] = (__bf16)a.w;
      r[4] = (__bf16)b.x; r[5] = (__bf16)b.y; r[6] = (__bf16)b.z; r[7] = (__bf16)b.w;
    } else {
      r = *(const bf16x8*)((const __bf16*)src + i);
    }
    *(bf16x8*)(dst + i) = r;
  }
}

// ---------------------------------------------------------------------------
// async 16B global -> LDS copy (gfx950 global_load_lds dwordx4)
// ---------------------------------------------------------------------------
__device__ __forceinline__ void g2lds16(const __bf16* g, __bf16* l)
{
  __builtin_amdgcn_global_load_lds(
      (const __attribute__((address_space(1))) void*)g,
      (__attribute__((address_space(3))) void*)l, 16, 0, 0);
}

// pack two f32 -> one u32 of two bf16 (RNE), single HW instruction
__device__ __forceinline__ unsigned cvtpk_bf16(float lo, float hi)
{
  unsigned r;
  asm("v_cvt_pk_bf16_f32 %0, %1, %2" : "=v"(r) : "v"(lo), "v"(hi));
  return r;
}

// ---------------------------------------------------------------------------
// m97-style GEMM: C = A * Bm^T. A: MxK bf16, Bm: NxK bf16. 128x128 tile,
// BK=64, 4 waves (2x2), global_load_lds width-16 staging (unpadded LDS).
// XCD-aware swizzle (nwg % 8 == 0 for all launches here).
// Output: bf16, or fp32 when (adaptive && *flagp).
// ---------------------------------------------------------------------------
__global__ __launch_bounds__(256) void gemm128(
    const __bf16* __restrict__ A, const __bf16* __restrict__ Bm,
    void* __restrict__ C, int M, int N, int K,
    const int* __restrict__ flagp, int adaptive)
{
  __shared__ __bf16 As[128][64];
  __shared__ __bf16 Bs[128][64];

  const int tid  = threadIdx.x;
  const int wv   = tid >> 6;
  const int lane = tid & 63;
  const int n16  = lane & 15;
  const int quad = lane >> 4;
  const int wm = (wv & 1) * 64, wn = (wv >> 1) * 64;

  const int nwgx = gridDim.x;
  const int id   = blockIdx.y * nwgx + blockIdx.x;
  const int cpx  = (nwgx * gridDim.y) >> 3;
  const int swz  = (id & 7) * cpx + (id >> 3);
  const int m0 = (swz % nwgx) * 128, n0 = (swz / nwgx) * 128;

  f32x4 acc[4][4];
#pragma unroll
  for (int i = 0; i < 4; i++)
#pragma unroll
    for (int j = 0; j < 4; j++) acc[i][j] = (f32x4){0.f, 0.f, 0.f, 0.f};

  const int trow = tid >> 3;          // 0..31
  const int tcol = (tid & 7) * 8;     // 0..56

  for (int k0 = 0; k0 < K; k0 += 64) {
#pragma unroll
    for (int p = 0; p < 4; p++) {
      g2lds16(A  + (size_t)(m0 + trow + p * 32) * K + k0 + tcol,
              &As[trow + p * 32][tcol]);
      g2lds16(Bm + (size_t)(n0 + trow + p * 32) * K + k0 + tcol,
              &Bs[trow + p * 32][tcol]);
    }
    __syncthreads();   // drains vmcnt(0): LDS is valid

#pragma unroll
    for (int kk = 0; kk < 2; kk++) {
      bf16x8 af[4], bf[4];
#pragma unroll
      for (int i = 0; i < 4; i++) {
        af[i] = *(const bf16x8*)&As[wm + i * 16 + n16][kk * 32 + quad * 8];
        bf[i] = *(const bf16x8*)&Bs[wn + i * 16 + n16][kk * 32 + quad * 8];
      }
#pragma unroll
      for (int i = 0; i < 4; i++)
#pragma unroll
        for (int j = 0; j < 4; j++)
          acc[i][j] = __builtin_amdgcn_mfma_f32_16x16x32_bf16(af[i], bf[j],
                                                              acc[i][j], 0, 0, 0);
    }
    __syncthreads();
  }

  const int f = adaptive ? *flagp : 0;
  const int rb = quad * 4;
#pragma unroll
  for (int i = 0; i < 4; i++)
#pragma unroll
    for (int j = 0; j < 4; j++)
#pragma unroll
      for (int r = 0; r < 4; r++) {
        const size_t idx = (size_t)(m0 + wm + i * 16 + rb + r) * N
                           + n0 + wn + j * 16 + n16;
        if (f) ((float*)C)[idx] = acc[i][j][r];
        else   ((__bf16*)C)[idx] = (__bf16)acc[i][j][r];
      }
}

// ---------------------------------------------------------------------------
// Fused rmsnorm+RoPE on q (stride 1024) and k (in fused kv, stride 2048),
// plus v mix (kv stride 2048, col +1024).
// ---------------------------------------------------------------------------
__global__ __launch_bounds__(256) void fuse_rope_vmix(
    const int* __restrict__ flagp,
    __hip_bfloat16* __restrict__ q,
    __hip_bfloat16* __restrict__ kv,
    const void* __restrict__ v1,
    const void* __restrict__ lambp)
{
  const int f    = *flagp;
  const int task = blockIdx.x * 4 + (threadIdx.x >> 6);
  const int lane = threadIdx.x & 63;
  const int h  = task & 15;
  const int bt = task >> 4;
  const int t  = bt & (T_ - 1);
  const size_t baseq = (size_t)bt * C_ + h * D_ + lane;
  const size_t basek = (size_t)bt * KVSTR_ + h * D_ + lane;

  const int j = lane & 31;
  const float inv = expf(-(float)j * (9.2103403719761836f / 32.0f));
  const float ang = (float)t * inv;
  const float cs = cosf(ang), sn = sinf(ang);
  const float EPS = 0.0078125f;

  {
    float xv = __bfloat162float(q[baseq]);
    float ss = xv * xv;
#pragma unroll
    for (int off = 32; off >= 1; off >>= 1) ss += __shfl_xor(ss, off);
    float r  = rsqrtf(ss * (1.0f / 64.0f) + EPS);
    float xn = xv * r;
    float pr = __shfl_xor(xn, 32);
    float yv = (lane < 32) ? (xn * cs + pr * sn) : (pr * -sn + xn * cs);
    q[baseq] = __float2bfloat16(yv);
  }
  {
    float xv = __bfloat162float(kv[basek]);
    float ss = xv * xv;
#pragma unroll
    for (int off = 32; off >= 1; off >>= 1) ss += __shfl_xor(ss, off);
    float r  = rsqrtf(ss * (1.0f / 64.0f) + EPS);
    float xn = xv * r;
    float pr = __shfl_xor(xn, 32);
    float yv = (lane < 32) ? (xn * cs + pr * sn) : (pr * -sn + xn * cs);
    kv[basek] = __float2bfloat16(yv);
  }
  {
    float lam = load1_adapt(lambp, 0, f);
    float vv  = __bfloat162float(kv[basek + 1024]);
    float v1v = load1_adapt(v1, baseq, f);
    kv[basek + 1024] = __float2bfloat16((1.0f - lam) * vv + lam * v1v);
  }
}

// ---------------------------------------------------------------------------
// Transpose mixed V (cols 1024..2047 of kv, stride 2048) -> PACKED V^T in
// fragment-linear layout:
//   pvt[ ((bh*32+it)*2+dh)*2048 + sc*512 + (l31+32*hi)*8 + j ]
//     = V[s = 64it+16sc+8hi+j][d = 32dh+l31]
// so attn's PV A-fragment load is one contiguous 1KB wave-load.
// ---------------------------------------------------------------------------
__global__ __launch_bounds__(256) void transp_v(
    const __bf16* __restrict__ kv, __bf16* __restrict__ pvt)
{
  __shared__ __bf16 Ts[64][72];
  const int bh = blockIdx.y;          // 0..63
  const int it = blockIdx.x;          // 0..31 (s-tile of 64)
  const int t0 = it * 64;
  const int b = bh >> 4, h = bh & 15;

  const int r = threadIdx.x >> 2;           // 0..63 (s-local)
  const int c = (threadIdx.x & 3) * 16;     // 0,16,32,48 (d)
  const __bf16* src = kv + (size_t)(b * T_ + t0 + r) * KVSTR_ + 1024 + h * D_ + c;
  *(bf16x8*)&Ts[r][c]     = *(const bf16x8*)src;
  *(bf16x8*)&Ts[r][c + 8] = *(const bf16x8*)(src + 8);
  __syncthreads();

  const int d  = threadIdx.x >> 2;          // 0..63
  const int sc = threadIdx.x & 3;           // s-chunk (16 wide)
  bf16x8 o0, o1;
#pragma unroll
  for (int jj = 0; jj < 8; jj++) {
    o0[jj] = Ts[sc * 16 + jj][d];           // hi=0: s-local 16sc+j
    o1[jj] = Ts[sc * 16 + 8 + jj][d];       // hi=1
  }
  const int dh = d >> 5, l31 = d & 31;
  __bf16* dst = pvt + (((size_t)bh * 32 + it) * 2 + dh) * 2048 + sc * 512 + l31 * 8;
  *(bf16x8*)dst         = o0;
  *(bf16x8*)(dst + 256) = o1;               // lane l31+32
}

// ---------------------------------------------------------------------------
// Pack rope'd K (cols 0..1023 of kv) into fragment-linear layout stored
// IN-PLACE in the dead V-columns (cols 1024..2047) of kv — disjoint from
// every byte this kernel reads (K cols), so no race; runs after transp_v
// has consumed V. Virtual packed chunk cid (8 elems):
//   physical = row (cid>>7), col 1024 + (cid&127)*8
//   value    = K[t = 64it+32st+l31][d = 16i+8hi+j]
// Every 512-elem fragment lies inside one row's contiguous V-half, so attn
// wave-loads stay single-segment coalesced.
// ---------------------------------------------------------------------------
__global__ __launch_bounds__(256) void pack_k(__bf16* kv)
{
  const int cid = blockIdx.x * 256 + threadIdx.x;   // 0 .. 2^20-1
  const int lane = cid & 63;
  const int i    = (cid >> 6) & 3;
  const int st   = (cid >> 8) & 1;
  const int it   = (cid >> 9) & 31;
  const int bh   = cid >> 14;                       // 0..63
  const int b = bh >> 4, h = bh & 15;
  const int l31 = lane & 31, hi = lane >> 5;
  const int t = 64 * it + 32 * st + l31;
  const int d = 16 * i + 8 * hi;
  bf16x8 v = *(const bf16x8*)(kv + (size_t)(b * T_ + t) * KVSTR_ + h * D_ + d);
  *(bf16x8*)(kv + (size_t)(cid >> 7) * KVSTR_ + 1024 + (cid & 127) * 8) = v;
}

// ---------------------------------------------------------------------------
// MFMA flash attention fwd (causal), 32x32x16 geometry, barrier-free,
// LDS-free, with FRAGMENT-LINEAR packed K (in kv V-columns) and packed V^T:
// every per-iteration load is one contiguous coalesced wave-load instead of
// a 32-line gather — removes the TA/L2-line-amplification wall that pinned
// rounds 3-6 at ~146us. Swapped QK^T + fixed-max softmax + cvt_pk/permlane
// P redistribution (zero LDS ops). Heavy blocks first. y aliases q.
// Packed K fragment f=st*4+i of (bh,it):
//   pk + ((bh*32+it)*4 + (f>>1))*2048 + 1024 + (f&1)*512 + lane*8
// ---------------------------------------------------------------------------
__global__ __launch_bounds__(256, 3) void attn_mfma(
    const __bf16* q,
    const __bf16* __restrict__ pk,
    const __bf16* __restrict__ pvt,
    __bf16* y)
{
  const int tid  = threadIdx.x;
  const int wv   = tid >> 6;
  const int lane = tid & 63;
  const int l31  = lane & 31;
  const int hi   = lane >> 5;

  const int id = blockIdx.y * gridDim.x + blockIdx.x;   // 0..1023
  const int bh = id & 63;                               // head task
  const int bx = id >> 6;                               // 0..15
  const int b = bh >> 4, h = bh & 15;
  const int q0 = (gridDim.x - 1 - bx) * 128;            // heavy first
  const size_t hb = (size_t)b * T_ * C_ + h * D_;       // q/y base (stride C_)

  const int qbase = q0 + wv * 32;

  // ---- Q fragments (B-op of swapped QK): lane holds Q[qbase+l31][16i+8hi+j]
  bf16x8 aq[4];
  {
    const __bf16* qp = q + hb + (size_t)(qbase + l31) * C_ + hi * 8;
#pragma unroll
    for (int i = 0; i < 4; i++) {
      aq[i] = *(const bf16x8*)(qp + 16 * i);
#pragma unroll
      for (int jj = 0; jj < 8; jj++)
        aq[i][jj] = (__bf16)((float)aq[i][jj] * 0.125f);
    }
  }

  f32x16 Ot0, Ot1;                 // O^T[d = 32*dh + 8g+4hi+m][q = l31]
#pragma unroll
  for (int r = 0; r < 16; r++) { Ot0[r] = 0.f; Ot1[r] = 0.f; }
  float l_lane = 0.f;

  const int niter = (qbase + 31) / 64 + 1;
  for (int it = 0; it < niter; it++) {
    const int s0 = it * 64;
    const int nst = (s0 + 32 <= qbase + 31) ? 2 : 1;

    // ---- packed K/V^T fragment loads: contiguous coalesced wave-loads ----
    const __bf16* pkb = pk  + (((size_t)bh * 32 + it) * 4) * KVSTR_ + 1024 + lane * 8;
    const __bf16* pvb = pvt + (((size_t)bh * 32 + it) * 2) * 2048 + lane * 8;
    bf16x8 kf[2][4], vf[2][4];
#pragma unroll
    for (int st = 0; st < 2; st++)
#pragma unroll
      for (int i = 0; i < 4; i++) {
        const int f = st * 4 + i;
        kf[st][i] = *(const bf16x8*)(pkb + (f >> 1) * KVSTR_ + (f & 1) * 512);
      }
#pragma unroll
    for (int dh = 0; dh < 2; dh++)
#pragma unroll
      for (int sc = 0; sc < 4; sc++)
        vf[dh][sc] = *(const bf16x8*)(pvb + dh * 2048 + sc * 512);

    bf16x8 pf[4];
#pragma unroll
    for (int st = 0; st < 2; st++) {
      if (st < nst) {
        // ---- S^T = K Q^T (4 chained k-chunks over D=64) ----
        f32x16 S;
#pragma unroll
        for (int r = 0; r < 16; r++) S[r] = 0.f;
        __builtin_amdgcn_s_setprio(1);
#pragma unroll
        for (int i = 0; i < 4; i++)
          S = __builtin_amdgcn_mfma_f32_32x32x16_bf16(kf[st][i], aq[i], S, 0, 0, 0);
        __builtin_amdgcn_s_setprio(0);

        // ---- causal mask (tile crosses the diagonal) ----
        if (s0 + 32 * st + 31 > qbase) {
          const int tg = qbase + l31;
#pragma unroll
          for (int r = 0; r < 16; r++) {
            const int sg = s0 + 32 * st + (r & 3) + 8 * (r >> 2) + 4 * hi;
            if (sg > tg) S[r] = -1e30f;
          }
        }

        // ---- fixed-max softmax: p = exp(S - 8), lane-local l ----
        float p[16];
#pragma unroll
        for (int r = 0; r < 16; r++) p[r] = __expf(S[r] - 8.0f);
#pragma unroll
        for (int r = 0; r < 16; r++) l_lane += p[r];

        // ---- pack s-adjacent pairs: wg[g][c] = (p[4g+2c], p[4g+2c+1]) ----
        unsigned wg[4][2];
#pragma unroll
        for (int g = 0; g < 4; g++) {
          wg[g][0] = cvtpk_bf16(p[4 * g + 0], p[4 * g + 1]);
          wg[g][1] = cvtpk_bf16(p[4 * g + 2], p[4 * g + 3]);
        }

        // ---- permlane32_swap: {x.lo,y.lo} = hi'=0 words, {x.hi,y.hi} = hi'=1
#pragma unroll
        for (int scl = 0; scl < 2; scl++) {
          unsigned x0 = wg[2 * scl][0], y0 = wg[2 * scl + 1][0];
          unsigned x1 = wg[2 * scl][1], y1 = wg[2 * scl + 1][1];
          asm volatile("v_permlane32_swap_b32 %0, %1" : "+v"(x0), "+v"(y0));
          asm volatile("v_permlane32_swap_b32 %0, %1" : "+v"(x1), "+v"(y1));
          union { u32x4 u; bf16x8 v8; } uw;
          uw.u[0] = x0; uw.u[1] = x1; uw.u[2] = y0; uw.u[3] = y1;
          pf[2 * st + scl] = uw.v8;
        }
      }
    }

    // ---- O^T += V^T P^T ----
    const int nsc = 2 * nst;
    __builtin_amdgcn_s_setprio(1);
#pragma unroll
    for (int sc = 0; sc < 4; sc++)
      if (sc < nsc) {
        Ot0 = __builtin_amdgcn_mfma_f32_32x32x16_bf16(vf[0][sc], pf[sc], Ot0, 0, 0, 0);
        Ot1 = __builtin_amdgcn_mfma_f32_32x32x16_bf16(vf[1][sc], pf[sc], Ot1, 0, 0, 0);
      }
    __builtin_amdgcn_s_setprio(0);
  }

  // ---- epilogue: l = sum over the two hi-halves of this q ----
  l_lane += __shfl_xor(l_lane, 32);
  const float linv = 1.0f / l_lane;
  const int qrow = qbase + l31;
#pragma unroll
  for (int g = 0; g < 4; g++) {
    bf16x4 o0, o1;
#pragma unroll
    for (int m = 0; m < 4; m++) {
      o0[m] = (__bf16)(Ot0[4 * g + m] * linv);
      o1[m] = (__bf16)(Ot1[4 * g + m] * linv);
    }
    const int d0 = 8 * g + 4 * hi;
    *(bf16x4*)(y + hb + (size_t)qrow * C_ + d0)      = o0;
    *(bf16x4*)(y + hb + (size_t)qrow * C_ + 32 + d0) = o1;
  }
}

// ---------------------------------------------------------------------------
__global__ __launch_bounds__(256) void copy_v1(
    const int* __restrict__ flagp, const void* __restrict__ v1, void* __restrict__ out)
{
  const int f = *flagp;
  const size_t nbytes = NE_ * (f ? 4u : 2u);
  const uint4* s = (const uint4*)v1;
  uint4* d = (uint4*)((char*)out + nbytes);
  const size_t n16 = nbytes / 16;
  for (size_t i = (size_t)blockIdx.x * 256 + threadIdx.x; i < n16;
       i += (size_t)gridDim.x * 256)
    d[i] = s[i];
}

// ---------------------------------------------------------------------------
extern "C" void kernel_launch(void* const* d_in, const int* in_sizes, int n_in,
                              void* d_out, int out_size, void* d_ws, size_t ws_size,
                              hipStream_t stream)
{
  const void* x    = d_in[0];
  const void* v1   = d_in[1];
  const void* Wq   = d_in[2];
  const void* Wk   = d_in[3];
  const void* Wv   = d_in[4];
  const void* Wp   = d_in[5];
  const void* lamb = d_in[6];

  // ws layout (bf16): xb | qw | Wq | Wk | Wv | Wp | flag  (~42 MB)
  // xb is dead after the QKV GEMMs -> reused as PACKED V^T (NE_ elems).
  __bf16* xb  = (__bf16*)d_ws;
  __bf16* qw  = xb + NE_;
  __bf16* wqb = qw + NE_;
  __bf16* wkb = wqb + (size_t)C_ * C_;
  __bf16* wvb = wkb + (size_t)C_ * C_;   // contiguous after wkb (fused N=2048)
  __bf16* wpb = wvb + (size_t)C_ * C_;
  int* flagp  = (int*)(wpb + (size_t)C_ * C_);
  __bf16* pvtb = xb;                      // packed V^T alias (16 MB)
  // fused K|V [M][2048] staged in d_out (32 MB). transp_v consumes the
  // V-columns; pack_k then overwrites those same (dead, disjoint-from-read)
  // V-columns with fragment-linear packed K. All dead before final writes.
  __bf16* kvw = (__bf16*)d_out;

  probe_dtype<<<1, 256, 0, stream>>>((const unsigned short*)x, flagp);

  cvt_bf16<<<4096, 256, 0, stream>>>(flagp, x,  xb,  (int)NE_);
  cvt_bf16<<<512,  256, 0, stream>>>(flagp, Wq, wqb, C_ * C_);
  cvt_bf16<<<512,  256, 0, stream>>>(flagp, Wk, wkb, C_ * C_);
  cvt_bf16<<<512,  256, 0, stream>>>(flagp, Wv, wvb, C_ * C_);
  cvt_bf16<<<512,  256, 0, stream>>>(flagp, Wp, wpb, C_ * C_);

  // Q GEMM (N=1024) and fused K|V GEMM (N=2048, Wk/Wv contiguous)
  gemm128<<<dim3(M_ / 128, 8),  256, 0, stream>>>(xb, wqb, qw,  M_, 1024, C_, flagp, 0);
  gemm128<<<dim3(M_ / 128, 16), 256, 0, stream>>>(xb, wkb, kvw, M_, 2048, C_, flagp, 0);

  fuse_rope_vmix<<<(M_ * H_) / 4, 256, 0, stream>>>(
      flagp, (__hip_bfloat16*)qw, (__hip_bfloat16*)kvw, v1, lamb);

  // V -> packed V^T (into xb), then K -> packed K (into kv's dead V-columns)
  transp_v<<<dim3(T_ / 64, B_ * H_), 256, 0, stream>>>(kvw, pvtb);
  pack_k<<<4096, 256, 0, stream>>>(kvw);

  attn_mfma<<<dim3(T_ / 128, B_ * H_), 256, 0, stream>>>(qw, kvw, pvtb, qw);

  gemm128<<<dim3(M_ / 128, 8), 256, 0, stream>>>(qw, wpb, d_out, M_, 1024, C_, flagp, 1);
  copy_v1<<<8192, 256, 0, stream>>>(flagp, v1, d_out);
}

// Round 9
// 371.364 us; speedup vs baseline: 1.2181x; 1.0183x over previous
//
#include <hip/hip_runtime.h>
#include <hip/hip_bf16.h>

typedef __bf16 bf16x8 __attribute__((ext_vector_type(8)));
typedef __bf16 bf16x4 __attribute__((ext_vector_type(4)));
typedef float  f32x4  __attribute__((ext_vector_type(4)));
typedef float  f32x16 __attribute__((ext_vector_type(16)));
typedef unsigned u32x4 __attribute__((ext_vector_type(4)));

#define B_ 4
#define T_ 2048
#define H_ 16
#define D_ 64
#define C_ 1024
#define M_ 8192                    // B*T
#define NE_ ((size_t)M_ * C_)      // elems per (M,C) tensor
#define KVSTR_ 2048                // row stride of fused K|V tensor

// ---------------------------------------------------------------------------
// Probe: flag=1 if inputs are fp32, flag=0 if bf16.
// ---------------------------------------------------------------------------
__global__ void probe_dtype(const unsigned short* __restrict__ x,
                            int* __restrict__ flag)
{
  __shared__ float red[256];
  float m = 0.0f;
  for (int i = threadIdx.x; i < 4096; i += 256) {
    unsigned int u = ((unsigned int)x[i]) << 16;
    float v = fabsf(__uint_as_float(u));
    if (!(v <= 1e30f)) v = 1e31f;
    m = fmaxf(m, v);
  }
  red[threadIdx.x] = m;
  __syncthreads();
  for (int s = 128; s > 0; s >>= 1) {
    if (threadIdx.x < s) red[threadIdx.x] = fmaxf(red[threadIdx.x], red[threadIdx.x + s]);
    __syncthreads();
  }
  if (threadIdx.x == 0) *flag = (red[0] > 100.0f) ? 1 : 0;
}

__device__ __forceinline__ float load1_adapt(const void* p, size_t idx, int f)
{
  if (f) return ((const float*)p)[idx];
  return __bfloat162float(((const __hip_bfloat16*)p)[idx]);
}

// ---------------------------------------------------------------------------
// Convert a tensor to bf16 (fp32 src if flag, else plain bf16 copy).
// ---------------------------------------------------------------------------
__global__ __launch_bounds__(256) void cvt_bf16(
    const int* __restrict__ flagp, const void* __restrict__ src,
    __bf16* __restrict__ dst, int n)
{
  const int f = *flagp;
  for (size_t i = ((size_t)blockIdx.x * 256 + threadIdx.x) * 8; i < (size_t)n;
       i += (size_t)gridDim.x * 2048) {
    bf16x8 r;
    if (f) {
      const float* pf = (const float*)src + i;
      float4 a = *(const float4*)pf;
      float4 b = *(const float4*)(pf + 4);
      r[0] = (__bf16)a.x; r[1] = (__bf16)a.y; r[2] = (__bf16)a.z; r[3] = (__bf16)a.w;
      r[4] = (__bf16)b.x; r[5] = (__bf16)b.y; r[6] = (__bf16)b.z; r[7] = (__bf16)b.w;
    } else {
      r = *(const bf16x8*)((const __bf16*)src + i);
    }
    *(bf16x8*)(dst + i) = r;
  }
}

// ---------------------------------------------------------------------------
// async 16B global -> LDS copy (gfx950 global_load_lds dwordx4)
// ---------------------------------------------------------------------------
__device__ __forceinline__ void g2lds16(const __bf16* g, __bf16* l)
{
  __builtin_amdgcn_global_load_lds(
      (const __attribute__((address_space(1))) void*)g,
      (__attribute__((address_space(3))) void*)l, 16, 0, 0);
}

// pack two f32 -> one u32 of two bf16 (RNE), single HW instruction
__device__ __forceinline__ unsigned cvtpk_bf16(float lo, float hi)
{
  unsigned r;
  asm("v_cvt_pk_bf16_f32 %0, %1, %2" : "=v"(r) : "v"(lo), "v"(hi));
  return r;
}

// ---------------------------------------------------------------------------
// m97-style GEMM: C = A * Bm^T. A: MxK bf16, Bm: NxK bf16. 128x128 tile,
// BK=64, 4 waves (2x2), global_load_lds width-16 staging (unpadded LDS).
// XCD mapping (L2-reuse): XCD j owns an A-STRIPE of gx/8 m-tiles and sweeps
// N fastest — the 2MB A-stripe stays L2-resident across all B panels
// (old mapping streamed the whole 16MB A through each 4MB L2 -> 133MB fetch).
// Requires gx%8==0 and gy a power of two (64x{8,16} here).
// Output: bf16, or fp32 when (adaptive && *flagp).
// ---------------------------------------------------------------------------
__global__ __launch_bounds__(256) void gemm128(
    const __bf16* __restrict__ A, const __bf16* __restrict__ Bm,
    void* __restrict__ C, int M, int N, int K,
    const int* __restrict__ flagp, int adaptive)
{
  __shared__ __bf16 As[128][64];
  __shared__ __bf16 Bs[128][64];

  const int tid  = threadIdx.x;
  const int wv   = tid >> 6;
  const int lane = tid & 63;
  const int n16  = lane & 15;
  const int quad = lane >> 4;
  const int wm = (wv & 1) * 64, wn = (wv >> 1) * 64;

  const int nwgx = gridDim.x;            // 64
  const int gy   = gridDim.y;            // 8 or 16 (power of two)
  const int id   = blockIdx.y * nwgx + blockIdx.x;
  const int xcd  = id & 7;
  const int p    = id >> 3;
  const int nt   = p & (gy - 1);                       // N sweeps fastest
  const int mt   = xcd * (nwgx >> 3) + (p >> (__ffs(gy) - 1));
  const int m0 = mt * 128, n0 = nt * 128;

  f32x4 acc[4][4];
#pragma unroll
  for (int i = 0; i < 4; i++)
#pragma unroll
    for (int j = 0; j < 4; j++) acc[i][j] = (f32x4){0.f, 0.f, 0.f, 0.f};

  const int trow = tid >> 3;          // 0..31
  const int tcol = (tid & 7) * 8;     // 0..56

  for (int k0 = 0; k0 < K; k0 += 64) {
#pragma unroll
    for (int p2 = 0; p2 < 4; p2++) {
      g2lds16(A  + (size_t)(m0 + trow + p2 * 32) * K + k0 + tcol,
              &As[trow + p2 * 32][tcol]);
      g2lds16(Bm + (size_t)(n0 + trow + p2 * 32) * K + k0 + tcol,
              &Bs[trow + p2 * 32][tcol]);
    }
    __syncthreads();   // drains vmcnt(0): LDS is valid

#pragma unroll
    for (int kk = 0; kk < 2; kk++) {
      bf16x8 af[4], bf[4];
#pragma unroll
      for (int i = 0; i < 4; i++) {
        af[i] = *(const bf16x8*)&As[wm + i * 16 + n16][kk * 32 + quad * 8];
        bf[i] = *(const bf16x8*)&Bs[wn + i * 16 + n16][kk * 32 + quad * 8];
      }
#pragma unroll
      for (int i = 0; i < 4; i++)
#pragma unroll
        for (int j = 0; j < 4; j++)
          acc[i][j] = __builtin_amdgcn_mfma_f32_16x16x32_bf16(af[i], bf[j],
                                                              acc[i][j], 0, 0, 0);
    }
    __syncthreads();
  }

  const int f = adaptive ? *flagp : 0;
  const int rb = quad * 4;
#pragma unroll
  for (int i = 0; i < 4; i++)
#pragma unroll
    for (int j = 0; j < 4; j++)
#pragma unroll
      for (int r = 0; r < 4; r++) {
        const size_t idx = (size_t)(m0 + wm + i * 16 + rb + r) * N
                           + n0 + wn + j * 16 + n16;
        if (f) ((float*)C)[idx] = acc[i][j][r];
        else   ((__bf16*)C)[idx] = (__bf16)acc[i][j][r];
      }
}

// ---------------------------------------------------------------------------
// Fused rmsnorm+RoPE on q (stride 1024) and k (in fused kv, stride 2048),
// plus v mix (kv stride 2048, col +1024). For the fp32 path (f==1) this
// kernel ALSO emits the v1 output copy (d_out + NE_ floats; disjoint from
// kvw's [0,32MB)) — copy_v1 then early-exits, saving a 32MB re-read.
// ---------------------------------------------------------------------------
__global__ __launch_bounds__(256) void fuse_rope_vmix(
    const int* __restrict__ flagp,
    __hip_bfloat16* __restrict__ q,
    __hip_bfloat16* __restrict__ kv,
    const void* __restrict__ v1,
    const void* __restrict__ lambp,
    void* __restrict__ outp)
{
  const int f    = *flagp;
  const int task = blockIdx.x * 4 + (threadIdx.x >> 6);
  const int lane = threadIdx.x & 63;
  const int h  = task & 15;
  const int bt = task >> 4;
  const int t  = bt & (T_ - 1);
  const size_t baseq = (size_t)bt * C_ + h * D_ + lane;
  const size_t basek = (size_t)bt * KVSTR_ + h * D_ + lane;

  const int j = lane & 31;
  const float inv = expf(-(float)j * (9.2103403719761836f / 32.0f));
  const float ang = (float)t * inv;
  const float cs = cosf(ang), sn = sinf(ang);
  const float EPS = 0.0078125f;

  {
    float xv = __bfloat162float(q[baseq]);
    float ss = xv * xv;
#pragma unroll
    for (int off = 32; off >= 1; off >>= 1) ss += __shfl_xor(ss, off);
    float r  = rsqrtf(ss * (1.0f / 64.0f) + EPS);
    float xn = xv * r;
    float pr = __shfl_xor(xn, 32);
    float yv = (lane < 32) ? (xn * cs + pr * sn) : (pr * -sn + xn * cs);
    q[baseq] = __float2bfloat16(yv);
  }
  {
    float xv = __bfloat162float(kv[basek]);
    float ss = xv * xv;
#pragma unroll
    for (int off = 32; off >= 1; off >>= 1) ss += __shfl_xor(ss, off);
    float r  = rsqrtf(ss * (1.0f / 64.0f) + EPS);
    float xn = xv * r;
    float pr = __shfl_xor(xn, 32);
    float yv = (lane < 32) ? (xn * cs + pr * sn) : (pr * -sn + xn * cs);
    kv[basek] = __float2bfloat16(yv);
  }
  {
    float lam = load1_adapt(lambp, 0, f);
    float vv  = __bfloat162float(kv[basek + 1024]);
    float v1v = load1_adapt(v1, baseq, f);
    kv[basek + 1024] = __float2bfloat16((1.0f - lam) * vv + lam * v1v);
    if (f) ((float*)outp)[NE_ + baseq] = v1v;   // fused v1 output copy (fp32)
  }
}

// ---------------------------------------------------------------------------
// Transpose mixed V (cols 1024..2047 of kv, stride 2048) -> PACKED V^T in
// fragment-linear layout:
//   pvt[ ((bh*32+it)*2+dh)*2048 + sc*512 + (l31+32*hi)*8 + j ]
//     = V[s = 64it+16sc+8hi+j][d = 32dh+l31]
// so attn's PV A-fragment load is one contiguous 1KB wave-load.
// ---------------------------------------------------------------------------
__global__ __launch_bounds__(256) void transp_v(
    const __bf16* __restrict__ kv, __bf16* __restrict__ pvt)
{
  __shared__ __bf16 Ts[64][72];
  const int bh = blockIdx.y;          // 0..63
  const int it = blockIdx.x;          // 0..31 (s-tile of 64)
  const int t0 = it * 64;
  const int b = bh >> 4, h = bh & 15;

  const int r = threadIdx.x >> 2;           // 0..63 (s-local)
  const int c = (threadIdx.x & 3) * 16;     // 0,16,32,48 (d)
  const __bf16* src = kv + (size_t)(b * T_ + t0 + r) * KVSTR_ + 1024 + h * D_ + c;
  *(bf16x8*)&Ts[r][c]     = *(const bf16x8*)src;
  *(bf16x8*)&Ts[r][c + 8] = *(const bf16x8*)(src + 8);
  __syncthreads();

  const int d  = threadIdx.x >> 2;          // 0..63
  const int sc = threadIdx.x & 3;           // s-chunk (16 wide)
  bf16x8 o0, o1;
#pragma unroll
  for (int jj = 0; jj < 8; jj++) {
    o0[jj] = Ts[sc * 16 + jj][d];           // hi=0: s-local 16sc+j
    o1[jj] = Ts[sc * 16 + 8 + jj][d];       // hi=1
  }
  const int dh = d >> 5, l31 = d & 31;
  __bf16* dst = pvt + (((size_t)bh * 32 + it) * 2 + dh) * 2048 + sc * 512 + l31 * 8;
  *(bf16x8*)dst         = o0;
  *(bf16x8*)(dst + 256) = o1;               // lane l31+32
}

// ---------------------------------------------------------------------------
// Pack rope'd K (cols 0..1023 of kv) into fragment-linear layout stored
// IN-PLACE in the dead V-columns (cols 1024..2047) of kv — disjoint from
// every byte this kernel reads (K cols), so no race; runs after transp_v
// has consumed V. Virtual packed chunk cid (8 elems):
//   physical = row (cid>>7), col 1024 + (cid&127)*8
//   value    = K[t = 64it+32st+l31][d = 16i+8hi+j]
// Every 512-elem fragment lies inside one row's contiguous V-half, so attn
// wave-loads stay single-segment coalesced.
// ---------------------------------------------------------------------------
__global__ __launch_bounds__(256) void pack_k(__bf16* kv)
{
  const int cid = blockIdx.x * 256 + threadIdx.x;   // 0 .. 2^20-1
  const int lane = cid & 63;
  const int i    = (cid >> 6) & 3;
  const int st   = (cid >> 8) & 1;
  const int it   = (cid >> 9) & 31;
  const int bh   = cid >> 14;                       // 0..63
  const int b = bh >> 4, h = bh & 15;
  const int l31 = lane & 31, hi = lane >> 5;
  const int t = 64 * it + 32 * st + l31;
  const int d = 16 * i + 8 * hi;
  bf16x8 v = *(const bf16x8*)(kv + (size_t)(b * T_ + t) * KVSTR_ + h * D_ + d);
  *(bf16x8*)(kv + (size_t)(cid >> 7) * KVSTR_ + 1024 + (cid & 127) * 8) = v;
}

// ---------------------------------------------------------------------------
// MFMA flash attention fwd (causal), 32x32x16 geometry, barrier-free,
// LDS-free, with FRAGMENT-LINEAR packed K (in kv V-columns) and packed V^T:
// every per-iteration load is one contiguous coalesced wave-load. Swapped
// QK^T + fixed-max softmax + cvt_pk/permlane P redistribution (zero LDS
// ops). Heavy blocks first. y aliases q.
// Packed K fragment f=st*4+i of (bh,it):
//   pk + ((bh*32+it)*4 + (f>>1))*2048 + 1024 + (f&1)*512 + lane*8
// ---------------------------------------------------------------------------
__global__ __launch_bounds__(256, 3) void attn_mfma(
    const __bf16* q,
    const __bf16* __restrict__ pk,
    const __bf16* __restrict__ pvt,
    __bf16* y)
{
  const int tid  = threadIdx.x;
  const int wv   = tid >> 6;
  const int lane = tid & 63;
  const int l31  = lane & 31;
  const int hi   = lane >> 5;

  const int id = blockIdx.y * gridDim.x + blockIdx.x;   // 0..1023
  const int bh = id & 63;                               // head task
  const int bx = id >> 6;                               // 0..15
  const int b = bh >> 4, h = bh & 15;
  const int q0 = (gridDim.x - 1 - bx) * 128;            // heavy first
  const size_t hb = (size_t)b * T_ * C_ + h * D_;       // q/y base (stride C_)

  const int qbase = q0 + wv * 32;

  // ---- Q fragments (B-op of swapped QK): lane holds Q[qbase+l31][16i+8hi+j]
  bf16x8 aq[4];
  {
    const __bf16* qp = q + hb + (size_t)(qbase + l31) * C_ + hi * 8;
#pragma unroll
    for (int i = 0; i < 4; i++) {
      aq[i] = *(const bf16x8*)(qp + 16 * i);
#pragma unroll
      for (int jj = 0; jj < 8; jj++)
        aq[i][jj] = (__bf16)((float)aq[i][jj] * 0.125f);
    }
  }

  f32x16 Ot0, Ot1;                 // O^T[d = 32*dh + 8g+4hi+m][q = l31]
#pragma unroll
  for (int r = 0; r < 16; r++) { Ot0[r] = 0.f; Ot1[r] = 0.f; }
  float l_lane = 0.f;

  const int niter = (qbase + 31) / 64 + 1;
  for (int it = 0; it < niter; it++) {
    const int s0 = it * 64;
    const int nst = (s0 + 32 <= qbase + 31) ? 2 : 1;

    // ---- packed K/V^T fragment loads: contiguous coalesced wave-loads ----
    const __bf16* pkb = pk  + (((size_t)bh * 32 + it) * 4) * KVSTR_ + 1024 + lane * 8;
    const __bf16* pvb = pvt + (((size_t)bh * 32 + it) * 2) * 2048 + lane * 8;
    bf16x8 kf[2][4], vf[2][4];
#pragma unroll
    for (int st = 0; st < 2; st++)
#pragma unroll
      for (int i = 0; i < 4; i++) {
        const int f = st * 4 + i;
        kf[st][i] = *(const bf16x8*)(pkb + (f >> 1) * KVSTR_ + (f & 1) * 512);
      }
#pragma unroll
    for (int dh = 0; dh < 2; dh++)
#pragma unroll
      for (int sc = 0; sc < 4; sc++)
        vf[dh][sc] = *(const bf16x8*)(pvb + dh * 2048 + sc * 512);

    bf16x8 pf[4];
#pragma unroll
    for (int st = 0; st < 2; st++) {
      if (st < nst) {
        // ---- S^T = K Q^T (4 chained k-chunks over D=64) ----
        f32x16 S;
#pragma unroll
        for (int r = 0; r < 16; r++) S[r] = 0.f;
        __builtin_amdgcn_s_setprio(1);
#pragma unroll
        for (int i = 0; i < 4; i++)
          S = __builtin_amdgcn_mfma_f32_32x32x16_bf16(kf[st][i], aq[i], S, 0, 0, 0);
        __builtin_amdgcn_s_setprio(0);

        // ---- causal mask (tile crosses the diagonal) ----
        if (s0 + 32 * st + 31 > qbase) {
          const int tg = qbase + l31;
#pragma unroll
          for (int r = 0; r < 16; r++) {
            const int sg = s0 + 32 * st + (r & 3) + 8 * (r >> 2) + 4 * hi;
            if (sg > tg) S[r] = -1e30f;
          }
        }

        // ---- fixed-max softmax: p = exp(S - 8), lane-local l ----
        float p[16];
#pragma unroll
        for (int r = 0; r < 16; r++) p[r] = __expf(S[r] - 8.0f);
#pragma unroll
        for (int r = 0; r < 16; r++) l_lane += p[r];

        // ---- pack s-adjacent pairs: wg[g][c] = (p[4g+2c], p[4g+2c+1]) ----
        unsigned wg[4][2];
#pragma unroll
        for (int g = 0; g < 4; g++) {
          wg[g][0] = cvtpk_bf16(p[4 * g + 0], p[4 * g + 1]);
          wg[g][1] = cvtpk_bf16(p[4 * g + 2], p[4 * g + 3]);
        }

        // ---- permlane32_swap: {x.lo,y.lo} = hi'=0 words, {x.hi,y.hi} = hi'=1
#pragma unroll
        for (int scl = 0; scl < 2; scl++) {
          unsigned x0 = wg[2 * scl][0], y0 = wg[2 * scl + 1][0];
          unsigned x1 = wg[2 * scl][1], y1 = wg[2 * scl + 1][1];
          asm volatile("v_permlane32_swap_b32 %0, %1" : "+v"(x0), "+v"(y0));
          asm volatile("v_permlane32_swap_b32 %0, %1" : "+v"(x1), "+v"(y1));
          union { u32x4 u; bf16x8 v8; } uw;
          uw.u[0] = x0; uw.u[1] = x1; uw.u[2] = y0; uw.u[3] = y1;
          pf[2 * st + scl] = uw.v8;
        }
      }
    }

    // ---- O^T += V^T P^T ----
    const int nsc = 2 * nst;
    __builtin_amdgcn_s_setprio(1);
#pragma unroll
    for (int sc = 0; sc < 4; sc++)
      if (sc < nsc) {
        Ot0 = __builtin_amdgcn_mfma_f32_32x32x16_bf16(vf[0][sc], pf[sc], Ot0, 0, 0, 0);
        Ot1 = __builtin_amdgcn_mfma_f32_32x32x16_bf16(vf[1][sc], pf[sc], Ot1, 0, 0, 0);
      }
    __builtin_amdgcn_s_setprio(0);
  }

  // ---- epilogue: l = sum over the two hi-halves of this q ----
  l_lane += __shfl_xor(l_lane, 32);
  const float linv = 1.0f / l_lane;
  const int qrow = qbase + l31;
#pragma unroll
  for (int g = 0; g < 4; g++) {
    bf16x4 o0, o1;
#pragma unroll
    for (int m = 0; m < 4; m++) {
      o0[m] = (__bf16)(Ot0[4 * g + m] * linv);
      o1[m] = (__bf16)(Ot1[4 * g + m] * linv);
    }
    const int d0 = 8 * g + 4 * hi;
    *(bf16x4*)(y + hb + (size_t)qrow * C_ + d0)      = o0;
    *(bf16x4*)(y + hb + (size_t)qrow * C_ + 32 + d0) = o1;
  }
}

// ---------------------------------------------------------------------------
// v1 output copy — only needed for the bf16 path (f==0); the fp32 path's
// copy is fused into fuse_rope_vmix (its dst is disjoint from kvw there).
// ---------------------------------------------------------------------------
__global__ __launch_bounds__(256) void copy_v1(
    const int* __restrict__ flagp, const void* __restrict__ v1, void* __restrict__ out)
{
  const int f = *flagp;
  if (f) return;                       // fp32 path: already written by rope
  const size_t nbytes = NE_ * 2u;
  const uint4* s = (const uint4*)v1;
  uint4* d = (uint4*)((char*)out + nbytes);
  const size_t n16 = nbytes / 16;
  for (size_t i = (size_t)blockIdx.x * 256 + threadIdx.x; i < n16;
       i += (size_t)gridDim.x * 256)
    d[i] = s[i];
}

// ---------------------------------------------------------------------------
extern "C" void kernel_launch(void* const* d_in, const int* in_sizes, int n_in,
                              void* d_out, int out_size, void* d_ws, size_t ws_size,
                              hipStream_t stream)
{
  const void* x    = d_in[0];
  const void* v1   = d_in[1];
  const void* Wq   = d_in[2];
  const void* Wk   = d_in[3];
  const void* Wv   = d_in[4];
  const void* Wp   = d_in[5];
  const void* lamb = d_in[6];

  // ws layout (bf16): xb | qw | Wq | Wk | Wv | Wp | flag  (~42 MB)
  // xb is dead after the QKV GEMMs -> reused as PACKED V^T (NE_ elems).
  __bf16* xb  = (__bf16*)d_ws;
  __bf16* qw  = xb + NE_;
  __bf16* wqb = qw + NE_;
  __bf16* wkb = wqb + (size_t)C_ * C_;
  __bf16* wvb = wkb + (size_t)C_ * C_;   // contiguous after wkb (fused N=2048)
  __bf16* wpb = wvb + (size_t)C_ * C_;
  int* flagp  = (int*)(wpb + (size_t)C_ * C_);
  __bf16* pvtb = xb;                      // packed V^T alias (16 MB)
  // fused K|V [M][2048] staged in d_out (32 MB). transp_v consumes the
  // V-columns; pack_k then overwrites those same (dead, disjoint-from-read)
  // V-columns with fragment-linear packed K. All dead before final writes.
  __bf16* kvw = (__bf16*)d_out;

  probe_dtype<<<1, 256, 0, stream>>>((const unsigned short*)x, flagp);

  cvt_bf16<<<4096, 256, 0, stream>>>(flagp, x,  xb,  (int)NE_);
  cvt_bf16<<<512,  256, 0, stream>>>(flagp, Wq, wqb, C_ * C_);
  cvt_bf16<<<512,  256, 0, stream>>>(flagp, Wk, wkb, C_ * C_);
  cvt_bf16<<<512,  256, 0, stream>>>(flagp, Wv, wvb, C_ * C_);
  cvt_bf16<<<512,  256, 0, stream>>>(flagp, Wp, wpb, C_ * C_);

  // Q GEMM (N=1024) and fused K|V GEMM (N=2048, Wk/Wv contiguous)
  gemm128<<<dim3(M_ / 128, 8),  256, 0, stream>>>(xb, wqb, qw,  M_, 1024, C_, flagp, 0);
  gemm128<<<dim3(M_ / 128, 16), 256, 0, stream>>>(xb, wkb, kvw, M_, 2048, C_, flagp, 0);

  fuse_rope_vmix<<<(M_ * H_) / 4, 256, 0, stream>>>(
      flagp, (__hip_bfloat16*)qw, (__hip_bfloat16*)kvw, v1, lamb, d_out);

  // V -> packed V^T (into xb), then K -> packed K (into kv's dead V-columns)
  transp_v<<<dim3(T_ / 64, B_ * H_), 256, 0, stream>>>(kvw, pvtb);
  pack_k<<<4096, 256, 0, stream>>>(kvw);

  attn_mfma<<<dim3(T_ / 128, B_ * H_), 256, 0, stream>>>(qw, kvw, pvtb, qw);

  gemm128<<<dim3(M_ / 128, 8), 256, 0, stream>>>(qw, wpb, d_out, M_, 1024, C_, flagp, 1);
  copy_v1<<<8192, 256, 0, stream>>>(flagp, v1, d_out);
}